// Round 3
// baseline (849.456 us; speedup 1.0000x reference)
//
#include <hip/hip_runtime.h>
#include <cstdint>

#define BATCH 16
#define NN 131072
#define NCOL 64
#define KOUT 500
#define NEGV (-1e30f)

// Separately-rounded IEEE ops (no FMA contraction) to match numpy/XLA-CPU
// float32 evaluation order in every expression that feeds a discrete decision.
__device__ __forceinline__ float fadd(float a, float b) { return __fadd_rn(a, b); }
__device__ __forceinline__ float fsub(float a, float b) { return __fsub_rn(a, b); }
__device__ __forceinline__ float fmul(float a, float b) { return __fmul_rn(a, b); }

// Box regression exactly as reference apply_regress (dy,dh with scales .1/.2)
__device__ __forceinline__ void regress(float ya, float yb, float dl0, float dl1,
                                        float& ny1, float& ny2) {
    float h  = fsub(yb, ya);
    float cy = fmul(fadd(yb, ya), 0.5f);
    float d0 = fmul(dl0, 0.1f);
    float d1 = fmul(dl1, 0.2f);
    cy = fadd(cy, fmul(d0, h));
    h  = fmul(h, expf(d1));
    ny1 = fsub(cy, fmul(0.5f, h));
    ny2 = fadd(cy, fmul(0.5f, h));
}

// softmax(logits)[1] exactly as jax.nn.softmax (subtract max, exp, normalize)
__device__ __forceinline__ float fg_score(float l0, float l1) {
    float mx = fmaxf(l0, l1);
    float e0 = expf(fsub(l0, mx));
    float e1 = expf(fsub(l1, mx));
    return e1 / fadd(e0, e1);
}

// ---------------------------------------------------------------------------
// K1: gather + softmax score + filter + box regression + bucket by (b, col)
// ---------------------------------------------------------------------------
__global__ void k_filter(const float* __restrict__ deltas,
                         const float* __restrict__ logits,
                         const float* __restrict__ anchors,
                         const int* __restrict__ vai,
                         int* __restrict__ cand_count,
                         float4* __restrict__ cand,
                         int cap) {
    int t = blockIdx.x * blockDim.x + threadIdx.x;
    if (t >= BATCH * NN) return;
    int b = t >> 17;          // N = 2^17
    int i = t & (NN - 1);
    int g = vai[t];
    size_t lbase = ((size_t)b * NN + g) * 2;
    float l0 = logits[lbase], l1 = logits[lbase + 1];
    float s = fg_score(l0, l1);
    if (!(s >= 0.7f)) return;
    const float* an = anchors + (size_t)t * 4;
    float ny1, ny2;
    regress(an[0], an[2], deltas[lbase], deltas[lbase + 1], ny1, ny2);
    int col = (int)(an[1] * 0.0625f);       // x1 = col*16 exactly
    int pos = atomicAdd(&cand_count[b * NCOL + col], 1);
    if (pos < cap)
        cand[(size_t)(b * NCOL + col) * cap + pos] =
            make_float4(s, ny1, ny2, __int_as_float(i));
}

// ---------------------------------------------------------------------------
// K2: per-(batch,col) greedy NMS, one wave per block, data in LDS.
// Suppression is column-local (cross-column IoU is exactly 0).
// Key = score_bits<<32 | (N-1-idx)<<10 | slot  ->  max key == (max score,
// min original index) tie-break, matching jnp.argmax first-occurrence.
// sc[] access is lane-private (stride-64), so the serial loop needs no barriers.
// ---------------------------------------------------------------------------
__global__ __launch_bounds__(64) void k_nms(const int* __restrict__ cand_count,
                                            const float4* __restrict__ cand,
                                            unsigned long long* __restrict__ surv,
                                            int* __restrict__ surv_count,
                                            int cap) {
    __shared__ float sc[1024], sy1[1024], sy2[1024];
    __shared__ unsigned int klo[1024];
    int bc = blockIdx.x;
    int lane = threadIdx.x;
    int cnt = cand_count[bc];
    if (cnt > cap) cnt = cap;
    for (int j = lane; j < cnt; j += 64) {
        float4 c = cand[(size_t)bc * cap + j];
        sc[j]  = c.x;
        sy1[j] = c.y;
        sy2[j] = c.z;
        int idx = __float_as_int(c.w);
        klo[j] = ((unsigned)(NN - 1 - idx) << 10) | (unsigned)j;
    }
    __syncthreads();
    unsigned long long* so = surv + (size_t)bc * KOUT;
    int ns = 0;
    for (int it = 0; it < cnt; ++it) {
        // argmax over active entries
        unsigned long long best = 0ull;
        for (int j = lane; j < cnt; j += 64) {
            float s = sc[j];
            if (s > NEGV) {
                unsigned long long key =
                    ((unsigned long long)__float_as_uint(s) << 32) | klo[j];
                if (key > best) best = key;
            }
        }
        for (int o = 32; o; o >>= 1) {
            unsigned long long other = __shfl_xor(best, o);
            if (other > best) best = other;
        }
        if (best == 0ull) break;      // no active candidates left
        if (lane == 0) so[ns] = best;
        ns++;
        if (ns == KOUT) break;        // >500 can never reach global top-500
        int js = (int)(best & 1023ull);
        float ya = sy1[js], yb = sy2[js];   // read-only LDS, written pre-sync
        float a1 = fmul(fsub(yb, ya), 16.0f);  // width exactly 16 -> bit-exact
        for (int j = lane; j < cnt; j += 64) {
            if (sc[j] > NEGV) {
                float yy1 = fmaxf(ya, sy1[j]);
                float yy2 = fminf(yb, sy2[j]);
                float inter = fmul(fmaxf(fsub(yy2, yy1), 0.0f), 16.0f);
                float a2 = fmul(fsub(sy2[j], sy1[j]), 16.0f);
                // denominator left-to-right: ((a1+a2)-inter)+1e-8, as np does
                float den = fadd(fsub(fadd(a1, a2), inter), 1e-8f);
                float iou = inter / den;
                if (iou > 0.3f) sc[j] = NEGV;   // selected box self-suppresses
            }
        }
    }
    if (lane == 0) surv_count[bc] = ns;
}

// ---------------------------------------------------------------------------
// K3: per-batch 64-way merge of sorted survivor lists -> global top-500.
// One wave per batch; lane c owns column c's list head.
// ---------------------------------------------------------------------------
__global__ __launch_bounds__(64) void k_merge(const unsigned long long* __restrict__ surv,
                                              const int* __restrict__ surv_count,
                                              int* __restrict__ sel) {
    int b = blockIdx.x;
    int lane = threadIdx.x;
    const unsigned long long* sv = surv + ((size_t)b * NCOL + lane) * KOUT;
    int cnt = surv_count[b * NCOL + lane];
    int ptr = 0;
    unsigned long long head = (cnt > 0) ? sv[0] : 0ull;
    unsigned long long nxt  = (cnt > 1) ? sv[1] : 0ull;   // speculative prefetch
    int* selb = sel + b * KOUT;
    for (int slot = 0; slot < KOUT; ++slot) {
        unsigned long long m = head;
        for (int o = 32; o; o >>= 1) {
            unsigned long long x = __shfl_xor(m, o);
            if (x > m) m = x;
        }
        if (m == 0ull) {   // exhausted: remaining slots invalid
            for (int s2 = slot + lane; s2 < KOUT; s2 += 64) selb[s2] = -1;
            return;
        }
        if (head == m) {   // unique winner (keys contain unique idx)
            selb[slot] = NN - 1 - (int)((m >> 10) & 0x1FFFFull);
            ptr++;
            head = nxt;
            nxt = (ptr + 1 < cnt) ? sv[ptr + 1] : 0ull;
        }
    }
}

// ---------------------------------------------------------------------------
// K4: recompute selected rows' box/score/logits, write padded outputs.
// out = [16,500,5] boxes+mask | [16,500,2] score+mask | [16,500,3] logits+mask
// ---------------------------------------------------------------------------
__global__ void k_out(const int* __restrict__ sel,
                      const float* __restrict__ deltas,
                      const float* __restrict__ logits,
                      const float* __restrict__ anchors,
                      const int* __restrict__ vai,
                      float* __restrict__ out) {
    int t = blockIdx.x * blockDim.x + threadIdx.x;
    if (t >= BATCH * KOUT) return;
    int b = t / KOUT;
    int i = sel[t];
    float y1 = 0, x1 = 0, y2 = 0, x2 = 0, s = 0, l0o = 0, l1o = 0, msk = 0;
    if (i >= 0) {
        int g = vai[(size_t)b * NN + i];
        size_t lbase = ((size_t)b * NN + g) * 2;
        float l0 = logits[lbase], l1 = logits[lbase + 1];
        s = fg_score(l0, l1);
        const float* an = anchors + ((size_t)b * NN + i) * 4;
        x1 = an[1];
        x2 = an[3];
        regress(an[0], an[2], deltas[lbase], deltas[lbase + 1], y1, y2);
        l0o = l0; l1o = l1; msk = 1.0f;
    }
    float* bo = out + (size_t)t * 5;
    bo[0] = y1; bo[1] = x1; bo[2] = y2; bo[3] = x2; bo[4] = msk;
    float* so = out + BATCH * KOUT * 5 + (size_t)t * 2;
    so[0] = s; so[1] = msk;
    float* lo = out + BATCH * KOUT * 7 + (size_t)t * 3;
    lo[0] = l0o; lo[1] = l1o; lo[2] = msk;
}

// ---------------------------------------------------------------------------
extern "C" void kernel_launch(void* const* d_in, const int* in_sizes, int n_in,
                              void* d_out, int out_size, void* d_ws, size_t ws_size,
                              hipStream_t stream) {
    const float* deltas  = (const float*)d_in[0];
    const float* logits  = (const float*)d_in[1];
    const float* anchors = (const float*)d_in[2];
    const int*   vai     = (const int*)d_in[3];
    float* out = (float*)d_out;

    // workspace layout (shrink cap if ws is small; 1024 is ~19 sigma headroom)
    int cap = 1024;
    auto need = [&](int c) -> size_t {
        size_t o = (size_t)BATCH * NCOL * 4 * 2 + (size_t)BATCH * KOUT * 4;
        o = (o + 15) & ~(size_t)15;
        o += (size_t)BATCH * NCOL * c * 16;
        o += (size_t)BATCH * NCOL * KOUT * 8;
        return o;
    };
    while (cap > 64 && need(cap) > ws_size) cap >>= 1;

    char* ws = (char*)d_ws;
    size_t off = 0;
    int* cand_count = (int*)(ws + off); off += (size_t)BATCH * NCOL * 4;
    int* surv_count = (int*)(ws + off); off += (size_t)BATCH * NCOL * 4;
    int* sel        = (int*)(ws + off); off += (size_t)BATCH * KOUT * 4;
    off = (off + 15) & ~(size_t)15;
    float4* cand = (float4*)(ws + off); off += (size_t)BATCH * NCOL * cap * 16;
    unsigned long long* surv = (unsigned long long*)(ws + off);

    hipMemsetAsync(cand_count, 0, (size_t)BATCH * NCOL * 4 * 2, stream);
    k_filter<<<(BATCH * NN + 255) / 256, 256, 0, stream>>>(
        deltas, logits, anchors, vai, cand_count, cand, cap);
    k_nms<<<BATCH * NCOL, 64, 0, stream>>>(cand_count, cand, surv, surv_count, cap);
    k_merge<<<BATCH, 64, 0, stream>>>(surv, surv_count, sel);
    k_out<<<(BATCH * KOUT + 255) / 256, 256, 0, stream>>>(
        sel, deltas, logits, anchors, vai, out);
}

// Round 5
// 752.113 us; speedup vs baseline: 1.1294x; 1.1294x over previous
//
#include <hip/hip_runtime.h>
#include <cstdint>

#define BATCH 16
#define NN 131072
#define NCOL 64
#define KOUT 500
#define NEGV (-1e30f)
#define GG 8

// Separately-rounded IEEE ops (no FMA contraction) to match numpy/XLA-CPU
// float32 evaluation order in every expression that feeds a discrete decision.
__device__ __forceinline__ float fadd(float a, float b) { return __fadd_rn(a, b); }
__device__ __forceinline__ float fsub(float a, float b) { return __fsub_rn(a, b); }
__device__ __forceinline__ float fmul(float a, float b) { return __fmul_rn(a, b); }

// Box regression exactly as reference apply_regress (dy,dh with scales .1/.2)
__device__ __forceinline__ void regress(float ya, float yb, float dl0, float dl1,
                                        float& ny1, float& ny2) {
    float h  = fsub(yb, ya);
    float cy = fmul(fadd(yb, ya), 0.5f);
    float d0 = fmul(dl0, 0.1f);
    float d1 = fmul(dl1, 0.2f);
    cy = fadd(cy, fmul(d0, h));
    h  = fmul(h, expf(d1));
    ny1 = fsub(cy, fmul(0.5f, h));
    ny2 = fadd(cy, fmul(0.5f, h));
}

// softmax(logits)[1] exactly as jax.nn.softmax (subtract max, exp, normalize)
__device__ __forceinline__ float fg_score(float l0, float l1) {
    float mx = fmaxf(l0, l1);
    float e0 = expf(fsub(l0, mx));
    float e1 = expf(fsub(l1, mx));
    return e1 / fadd(e0, e1);
}

// Full-wave (64-lane) max of a u64 key. DPP path: 6 VALU-latency steps
// (row_shr 1/2/4/8 within rows of 16, then row_bcast15/31 across rows)
// vs ~270 cy for the 6-level ds_bpermute shfl butterfly.
__device__ __forceinline__ unsigned long long wave_max_u64(unsigned long long v) {
#if __has_builtin(__builtin_amdgcn_update_dpp)
    unsigned hi = (unsigned)(v >> 32), lo = (unsigned)(v & 0xffffffffull);
#define DPP_STEP(C)                                                                     \
    {                                                                                   \
        unsigned ohi = (unsigned)__builtin_amdgcn_update_dpp((int)hi, (int)hi, C, 0xf, 0xf, false); \
        unsigned olo = (unsigned)__builtin_amdgcn_update_dpp((int)lo, (int)lo, C, 0xf, 0xf, false); \
        if (ohi > hi || (ohi == hi && olo > lo)) { hi = ohi; lo = olo; }                \
    }
    DPP_STEP(0x111)  // row_shr:1
    DPP_STEP(0x112)  // row_shr:2
    DPP_STEP(0x114)  // row_shr:4
    DPP_STEP(0x118)  // row_shr:8   -> lane 15 of each row-of-16 has row max
    DPP_STEP(0x142)  // row_bcast:15 -> lane31 = rows0-1, lane63 = rows2-3
    DPP_STEP(0x143)  // row_bcast:31 -> lane63 = all 64
#undef DPP_STEP
    unsigned long long m = ((unsigned long long)hi << 32) | lo;
    return __shfl(m, 63);
#else
    for (int o = 32; o; o >>= 1) {
        unsigned long long x = __shfl_xor(v, o);
        if (x > v) v = x;
    }
    return v;
#endif
}

// ---------------------------------------------------------------------------
// K1: gather + softmax + filter + regression + bucket scatter, ILP x8.
// All loads for 8 items are issued before any use -> ~32 loads in flight
// per wave (v1 had ~2: latency-bound, VALUBusy 1.7%).
// ---------------------------------------------------------------------------
__global__ __launch_bounds__(256) void k_filter(const float* __restrict__ deltas,
                                                const float* __restrict__ logits,
                                                const float* __restrict__ anchors,
                                                const int* __restrict__ vai,
                                                int* __restrict__ cand_count,
                                                float4* __restrict__ cand,
                                                int cap) {
    const int TOT = (BATCH * NN) / GG;  // 262144 threads, item k = t + k*TOT
    int t = blockIdx.x * blockDim.x + threadIdx.x;
    int g[GG];
#pragma unroll
    for (int k = 0; k < GG; ++k) g[k] = vai[t + k * TOT];
    float2 lg[GG], dl[GG];
#pragma unroll
    for (int k = 0; k < GG; ++k) {
        int id = t + k * TOT;
        size_t lbase = (((size_t)(id >> 17)) * NN + g[k]) * 2;
        lg[k] = *(const float2*)(logits + lbase);
        dl[k] = *(const float2*)(deltas + lbase);
    }
    float4 an[GG];
#pragma unroll
    for (int k = 0; k < GG; ++k) an[k] = ((const float4*)anchors)[t + k * TOT];
#pragma unroll
    for (int k = 0; k < GG; ++k) {
        float s = fg_score(lg[k].x, lg[k].y);
        if (!(s >= 0.7f)) continue;
        int id = t + k * TOT;
        int b = id >> 17;
        int i = id & (NN - 1);
        float ny1, ny2;
        regress(an[k].x, an[k].z, dl[k].x, dl[k].y, ny1, ny2);
        int col = (int)(an[k].y * 0.0625f);  // x1 = col*16 exactly
        int pos = atomicAdd(&cand_count[b * NCOL + col], 1);
        if (pos < cap)
            cand[(size_t)(b * NCOL + col) * cap + pos] =
                make_float4(s, ny1, ny2, __int_as_float(i));
    }
}

// ---------------------------------------------------------------------------
// K2: per-(batch,col) greedy NMS, one wave per block, fused scan.
// Per selection: ONE lane-private stride-64 sweep that both suppresses and
// computes the max surviving key (v1 did two sweeps + shfl butterfly).
// key[j]==0 means inactive. key = score_bits<<32 | (N-1-idx)<<10 | slot:
// max key == (max score, min original idx), matching jnp.argmax ties.
// key[] slices are lane-private (read AND write), sy1/sy2 read-only after
// load -> no barriers needed in the serial loop (single wave, in-order LDS).
// ---------------------------------------------------------------------------
__global__ __launch_bounds__(64) void k_nms(const int* __restrict__ cand_count,
                                            const float4* __restrict__ cand,
                                            unsigned long long* __restrict__ surv,
                                            int* __restrict__ surv_count,
                                            int cap) {
    __shared__ unsigned long long key[1024];
    __shared__ float sy1[1024], sy2[1024];
    int bc = blockIdx.x;
    int lane = threadIdx.x;
    int cnt = cand_count[bc];
    if (cnt > cap) cnt = cap;
    for (int j = lane; j < cnt; j += 64) {
        float4 c = cand[(size_t)bc * cap + j];
        int idx = __float_as_int(c.w);
        key[j] = ((unsigned long long)__float_as_uint(c.x) << 32) |
                 ((unsigned)(NN - 1 - idx) << 10) | (unsigned)j;
        sy1[j] = c.y;
        sy2[j] = c.z;
    }
    __syncthreads();
    unsigned long long* so = surv + (size_t)bc * KOUT;
    // initial argmax
    unsigned long long best = 0ull;
    for (int j = lane; j < cnt; j += 64) {
        unsigned long long k = key[j];
        if (k > best) best = k;
    }
    best = wave_max_u64(best);
    int ns = 0;
    while (best != 0ull) {
        if (lane == 0) so[ns] = best;
        ns++;
        if (ns == KOUT) break;  // >500 per column can never reach global top-500
        int js = (int)(best & 1023ull);
        float ya = sy1[js], yb = sy2[js];
        float a1 = fmul(fsub(yb, ya), 16.0f);  // width exactly 16 -> bit-exact 1D IoU
        unsigned long long nb = 0ull;
        for (int j = lane; j < cnt; j += 64) {
            unsigned long long k = key[j];
            if (k != 0ull) {
                float yy1 = fmaxf(ya, sy1[j]);
                float yy2 = fminf(yb, sy2[j]);
                float inter = fmul(fmaxf(fsub(yy2, yy1), 0.0f), 16.0f);
                float a2 = fmul(fsub(sy2[j], sy1[j]), 16.0f);
                // denominator left-to-right: ((a1+a2)-inter)+1e-8, as np does
                float den = fadd(fsub(fadd(a1, a2), inter), 1e-8f);
                float iou = inter / den;
                if (iou > 0.3f) key[j] = 0ull;  // selected box self-suppresses too
                else if (k > nb) nb = k;        // fused next-argmax
            }
        }
        best = wave_max_u64(nb);
    }
    if (lane == 0) surv_count[bc] = ns;
}

// ---------------------------------------------------------------------------
// K3: per-batch 64-way merge of sorted survivor lists -> global top-500.
// One wave per batch; lane c owns column c's list head. DPP max reduce.
// ---------------------------------------------------------------------------
__global__ __launch_bounds__(64) void k_merge(const unsigned long long* __restrict__ surv,
                                              const int* __restrict__ surv_count,
                                              int* __restrict__ sel) {
    int b = blockIdx.x;
    int lane = threadIdx.x;
    const unsigned long long* sv = surv + ((size_t)b * NCOL + lane) * KOUT;
    int cnt = surv_count[b * NCOL + lane];
    int ptr = 0;
    unsigned long long head = (cnt > 0) ? sv[0] : 0ull;
    unsigned long long nxt  = (cnt > 1) ? sv[1] : 0ull;  // speculative prefetch
    int* selb = sel + b * KOUT;
    for (int slot = 0; slot < KOUT; ++slot) {
        unsigned long long m = wave_max_u64(head);
        if (m == 0ull) {  // exhausted: remaining slots invalid
            for (int s2 = slot + lane; s2 < KOUT; s2 += 64) selb[s2] = -1;
            return;
        }
        if (head == m) {  // unique winner (keys contain unique idx)
            selb[slot] = NN - 1 - (int)((m >> 10) & 0x1FFFFull);
            ptr++;
            head = nxt;
            nxt = (ptr + 1 < cnt) ? sv[ptr + 1] : 0ull;
        }
    }
}

// ---------------------------------------------------------------------------
// K4: recompute selected rows' box/score/logits, write padded outputs.
// out = [16,500,5] boxes+mask | [16,500,2] score+mask | [16,500,3] logits+mask
// ---------------------------------------------------------------------------
__global__ void k_out(const int* __restrict__ sel,
                      const float* __restrict__ deltas,
                      const float* __restrict__ logits,
                      const float* __restrict__ anchors,
                      const int* __restrict__ vai,
                      float* __restrict__ out) {
    int t = blockIdx.x * blockDim.x + threadIdx.x;
    if (t >= BATCH * KOUT) return;
    int b = t / KOUT;
    int i = sel[t];
    float y1 = 0, x1 = 0, y2 = 0, x2 = 0, s = 0, l0o = 0, l1o = 0, msk = 0;
    if (i >= 0) {
        int g = vai[(size_t)b * NN + i];
        size_t lbase = ((size_t)b * NN + g) * 2;
        float l0 = logits[lbase], l1 = logits[lbase + 1];
        s = fg_score(l0, l1);
        const float* an = anchors + ((size_t)b * NN + i) * 4;
        x1 = an[1];
        x2 = an[3];
        regress(an[0], an[2], deltas[lbase], deltas[lbase + 1], y1, y2);
        l0o = l0; l1o = l1; msk = 1.0f;
    }
    float* bo = out + (size_t)t * 5;
    bo[0] = y1; bo[1] = x1; bo[2] = y2; bo[3] = x2; bo[4] = msk;
    float* so = out + BATCH * KOUT * 5 + (size_t)t * 2;
    so[0] = s; so[1] = msk;
    float* lo = out + BATCH * KOUT * 7 + (size_t)t * 3;
    lo[0] = l0o; lo[1] = l1o; lo[2] = msk;
}

// ---------------------------------------------------------------------------
extern "C" void kernel_launch(void* const* d_in, const int* in_sizes, int n_in,
                              void* d_out, int out_size, void* d_ws, size_t ws_size,
                              hipStream_t stream) {
    const float* deltas  = (const float*)d_in[0];
    const float* logits  = (const float*)d_in[1];
    const float* anchors = (const float*)d_in[2];
    const int*   vai     = (const int*)d_in[3];
    float* out = (float*)d_out;

    // workspace layout (shrink cap if ws is small; 1024 is ~19 sigma headroom)
    int cap = 1024;
    auto need = [&](int c) -> size_t {
        size_t o = (size_t)BATCH * NCOL * 4 * 2 + (size_t)BATCH * KOUT * 4;
        o = (o + 15) & ~(size_t)15;
        o += (size_t)BATCH * NCOL * c * 16;
        o += (size_t)BATCH * NCOL * KOUT * 8;
        return o;
    };
    while (cap > 64 && need(cap) > ws_size) cap >>= 1;

    char* ws = (char*)d_ws;
    size_t off = 0;
    int* cand_count = (int*)(ws + off); off += (size_t)BATCH * NCOL * 4;
    int* surv_count = (int*)(ws + off); off += (size_t)BATCH * NCOL * 4;
    int* sel        = (int*)(ws + off); off += (size_t)BATCH * KOUT * 4;
    off = (off + 15) & ~(size_t)15;
    float4* cand = (float4*)(ws + off); off += (size_t)BATCH * NCOL * cap * 16;
    unsigned long long* surv = (unsigned long long*)(ws + off);

    hipMemsetAsync(cand_count, 0, (size_t)BATCH * NCOL * 4 * 2, stream);
    k_filter<<<(BATCH * NN / GG) / 256, 256, 0, stream>>>(
        deltas, logits, anchors, vai, cand_count, cand, cap);
    k_nms<<<BATCH * NCOL, 64, 0, stream>>>(cand_count, cand, surv, surv_count, cap);
    k_merge<<<BATCH, 64, 0, stream>>>(surv, surv_count, sel);
    k_out<<<(BATCH * KOUT + 255) / 256, 256, 0, stream>>>(
        sel, deltas, logits, anchors, vai, out);
}

// Round 6
// 509.066 us; speedup vs baseline: 1.6687x; 1.4774x over previous
//
#include <hip/hip_runtime.h>
#include <cstdint>

#define BATCH 16
#define NN 131072
#define NCOL 64
#define KOUT 500
#define GG 8
typedef unsigned long long u64;

// Separately-rounded IEEE ops (no FMA contraction) to match numpy/XLA-CPU
// float32 evaluation order in every expression that feeds a discrete decision.
__device__ __forceinline__ float fadd(float a, float b) { return __fadd_rn(a, b); }
__device__ __forceinline__ float fsub(float a, float b) { return __fsub_rn(a, b); }
__device__ __forceinline__ float fmul(float a, float b) { return __fmul_rn(a, b); }

// Box regression exactly as reference apply_regress (dy,dh with scales .1/.2)
__device__ __forceinline__ void regress(float ya, float yb, float dl0, float dl1,
                                        float& ny1, float& ny2) {
    float h  = fsub(yb, ya);
    float cy = fmul(fadd(yb, ya), 0.5f);
    float d0 = fmul(dl0, 0.1f);
    float d1 = fmul(dl1, 0.2f);
    cy = fadd(cy, fmul(d0, h));
    h  = fmul(h, expf(d1));
    ny1 = fsub(cy, fmul(0.5f, h));
    ny2 = fadd(cy, fmul(0.5f, h));
}

// softmax(logits)[1] exactly as jax.nn.softmax (subtract max, exp, normalize)
__device__ __forceinline__ float fg_score(float l0, float l1) {
    float mx = fmaxf(l0, l1);
    float e0 = expf(fsub(l0, mx));
    float e1 = expf(fsub(l1, mx));
    return e1 / fadd(e0, e1);
}

// Full-wave (64-lane) max of a u64 key via DPP (row_shr then row_bcast).
__device__ __forceinline__ u64 wave_max_u64(u64 v) {
#if __has_builtin(__builtin_amdgcn_update_dpp)
    unsigned hi = (unsigned)(v >> 32), lo = (unsigned)(v & 0xffffffffull);
#define DPP_STEP(C)                                                                     \
    {                                                                                   \
        unsigned ohi = (unsigned)__builtin_amdgcn_update_dpp((int)hi, (int)hi, C, 0xf, 0xf, false); \
        unsigned olo = (unsigned)__builtin_amdgcn_update_dpp((int)lo, (int)lo, C, 0xf, 0xf, false); \
        if (ohi > hi || (ohi == hi && olo > lo)) { hi = ohi; lo = olo; }                \
    }
    DPP_STEP(0x111)  // row_shr:1
    DPP_STEP(0x112)  // row_shr:2
    DPP_STEP(0x114)  // row_shr:4
    DPP_STEP(0x118)  // row_shr:8
    DPP_STEP(0x142)  // row_bcast:15
    DPP_STEP(0x143)  // row_bcast:31 -> lane63 has the max
#undef DPP_STEP
    u64 m = ((u64)hi << 32) | lo;
    return __shfl(m, 63);
#else
    for (int o = 32; o; o >>= 1) {
        u64 x = __shfl_xor(v, o);
        if (x > v) v = x;
    }
    return v;
#endif
}

// ---------------------------------------------------------------------------
// K1: gather + softmax + filter + regression + bucket scatter, ILP x8.
// ---------------------------------------------------------------------------
__global__ __launch_bounds__(256) void k_filter(const float* __restrict__ deltas,
                                                const float* __restrict__ logits,
                                                const float* __restrict__ anchors,
                                                const int* __restrict__ vai,
                                                int* __restrict__ cand_count,
                                                float4* __restrict__ cand,
                                                int cap) {
    const int TOT = (BATCH * NN) / GG;  // 262144 threads, item k = t + k*TOT
    int t = blockIdx.x * blockDim.x + threadIdx.x;
    int g[GG];
#pragma unroll
    for (int k = 0; k < GG; ++k) g[k] = vai[t + k * TOT];
    float2 lg[GG], dl[GG];
#pragma unroll
    for (int k = 0; k < GG; ++k) {
        int id = t + k * TOT;
        size_t lbase = (((size_t)(id >> 17)) * NN + g[k]) * 2;
        lg[k] = *(const float2*)(logits + lbase);
        dl[k] = *(const float2*)(deltas + lbase);
    }
    float4 an[GG];
#pragma unroll
    for (int k = 0; k < GG; ++k) an[k] = ((const float4*)anchors)[t + k * TOT];
#pragma unroll
    for (int k = 0; k < GG; ++k) {
        float s = fg_score(lg[k].x, lg[k].y);
        if (!(s >= 0.7f)) continue;
        int id = t + k * TOT;
        int b = id >> 17;
        int i = id & (NN - 1);
        float ny1, ny2;
        regress(an[k].x, an[k].z, dl[k].x, dl[k].y, ny1, ny2);
        int col = (int)(an[k].y * 0.0625f);  // x1 = col*16 exactly
        int pos = atomicAdd(&cand_count[b * NCOL + col], 1);
        if (pos < cap)
            cand[(size_t)(b * NCOL + col) * cap + pos] =
                make_float4(s, ny1, ny2, __int_as_float(i));
    }
}

// ---------------------------------------------------------------------------
// K2: per-(batch,col) greedy NMS, one wave per block, STATICALLY UNROLLED
// fused sweep. LDS padded to fixed 1024 slots (key=0 => inactive) so every
// sweep is 16 unrolled chunks (uniform-branch skip past cnt) -> LDS loads
// pipeline instead of serializing on a runtime trip count.
// key = score_bits<<32 | (N-1-idx)<<10 | slot : max key == (max score, min
// original idx), matching jnp.argmax first-occurrence ties. key[] slices are
// lane-private -> no barriers in the serial loop (single wave, in-order LDS).
// ---------------------------------------------------------------------------
__global__ __launch_bounds__(64) void k_nms(const int* __restrict__ cand_count,
                                            const float4* __restrict__ cand,
                                            u64* __restrict__ surv,
                                            int* __restrict__ surv_count,
                                            int cap) {
    __shared__ u64 key[1024];
    __shared__ float sy1[1024], sy2[1024];
    int bc = blockIdx.x;
    int lane = threadIdx.x;
    int cnt = cand_count[bc];
    if (cnt > cap) cnt = cap;
    if (cnt > 1024) cnt = 1024;
#pragma unroll
    for (int k = 0; k < 16; ++k) {  // zero-fill pad (single wave: ordered LDS)
        int j = lane + (k << 6);
        key[j] = 0ull; sy1[j] = 0.0f; sy2[j] = 0.0f;
    }
    for (int j = lane; j < cnt; j += 64) {
        float4 c = cand[(size_t)bc * cap + j];
        int idx = __float_as_int(c.w);
        key[j] = ((u64)__float_as_uint(c.x) << 32) |
                 ((unsigned)(NN - 1 - idx) << 10) | (unsigned)j;
        sy1[j] = c.y;
        sy2[j] = c.z;
    }
    u64 best = 0ull;
#pragma unroll
    for (int k = 0; k < 16; ++k) {
        if ((k << 6) < cnt) {
            u64 v = key[lane + (k << 6)];
            if (v > best) best = v;
        }
    }
    best = wave_max_u64(best);
    u64* so = surv + (size_t)bc * KOUT;
    int ns = 0;
    while (best != 0ull) {
        if (lane == 0) so[ns] = best;
        ns++;
        if (ns == KOUT) break;  // >500 per column can never reach global top-500
        int js = (int)(best & 1023ull);
        float ya = sy1[js], yb = sy2[js];
        float a1 = fmul(fsub(yb, ya), 16.0f);  // width exactly 16 -> bit-exact 1D IoU
        u64 nb = 0ull;
#pragma unroll
        for (int k = 0; k < 16; ++k) {
            if ((k << 6) < cnt) {
                int j = lane + (k << 6);
                u64 v = key[j];
                float y1 = sy1[j], y2 = sy2[j];
                float yy1 = fmaxf(ya, y1);
                float yy2 = fminf(yb, y2);
                float inter = fmul(fmaxf(fsub(yy2, yy1), 0.0f), 16.0f);
                float a2 = fmul(fsub(y2, y1), 16.0f);
                // denominator left-to-right: ((a1+a2)-inter)+1e-8, as np does
                float den = fadd(fsub(fadd(a1, a2), inter), 1e-8f);
                float iou = inter / den;  // exact IEEE div (decision-feeding)
                if (v != 0ull) {
                    if (iou > 0.3f) key[j] = 0ull;  // selected box self-suppresses
                    else if (v > nb) nb = v;        // fused next-argmax
                }
            }
        }
        best = wave_max_u64(nb);
    }
    if (lane == 0) surv_count[bc] = ns;
}

// ---------------------------------------------------------------------------
// K3: one level of a pairwise merge tree. Block (b,m) merges sorted
// (descending, unique-key) lists (b,2m) and (b,2m+1) -> list (b,m), output
// capped at KOUT (exact: rank>=500 within a pair => rank>=500 globally).
// Merge-path: each output element found by a diagonal binary search in LDS.
// ---------------------------------------------------------------------------
__global__ __launch_bounds__(256) void k_mergeL(const u64* __restrict__ in,
                                                const int* __restrict__ incnt,
                                                u64* __restrict__ outb,
                                                int* __restrict__ outcnt,
                                                int nm) {
    __shared__ u64 A[512], B[512];
    int bid = blockIdx.x;
    int b = bid / nm, m = bid % nm;
    int ia = b * 64 + 2 * m, ib = ia + 1;
    int nA = incnt[ia]; if (nA > KOUT) nA = KOUT;
    int nB = incnt[ib]; if (nB > KOUT) nB = KOUT;
    const u64* pA = in + (size_t)ia * KOUT;
    const u64* pB = in + (size_t)ib * KOUT;
    for (int j = threadIdx.x; j < nA; j += 256) A[j] = pA[j];
    for (int j = threadIdx.x; j < nB; j += 256) B[j] = pB[j];
    __syncthreads();
    int L = nA + nB;
    if (L > KOUT) L = KOUT;
    u64* po = outb + (size_t)(b * 64 + m) * KOUT;
    for (int k = threadIdx.x; k < L; k += 256) {
        int lo = k - nB; if (lo < 0) lo = 0;
        int hi = k < nA ? k : nA;
        while (lo < hi) {  // find i = #elements taken from A among top-k
            int mid = (lo + hi) >> 1;
            if (A[mid] > B[k - mid - 1]) lo = mid + 1;
            else hi = mid;
        }
        int i = lo, j = k - lo;
        u64 v = (i < nA && (j >= nB || A[i] > B[j])) ? A[i] : B[j];
        po[k] = v;
    }
    if (threadIdx.x == 0) outcnt[b * 64 + m] = L;
}

// ---------------------------------------------------------------------------
// K4: read final merged top-500 list per batch; recompute box/score/logits.
// out = [16,500,5] boxes+mask | [16,500,2] score+mask | [16,500,3] logits+mask
// ---------------------------------------------------------------------------
__global__ void k_out(const u64* __restrict__ finalk,
                      const int* __restrict__ cntF,
                      const float* __restrict__ deltas,
                      const float* __restrict__ logits,
                      const float* __restrict__ anchors,
                      const int* __restrict__ vai,
                      float* __restrict__ out) {
    int t = blockIdx.x * blockDim.x + threadIdx.x;
    if (t >= BATCH * KOUT) return;
    int b = t / KOUT;
    int r = t % KOUT;
    int cnt = cntF[b * 64];
    float y1 = 0, x1 = 0, y2 = 0, x2 = 0, s = 0, l0o = 0, l1o = 0, msk = 0;
    if (r < cnt) {
        u64 key = finalk[(size_t)(b * 64) * KOUT + r];
        int i = NN - 1 - (int)((key >> 10) & 0x1FFFFull);
        int g = vai[(size_t)b * NN + i];
        size_t lbase = ((size_t)b * NN + g) * 2;
        float l0 = logits[lbase], l1 = logits[lbase + 1];
        s = fg_score(l0, l1);
        const float* an = anchors + ((size_t)b * NN + i) * 4;
        x1 = an[1];
        x2 = an[3];
        regress(an[0], an[2], deltas[lbase], deltas[lbase + 1], y1, y2);
        l0o = l0; l1o = l1; msk = 1.0f;
    }
    float* bo = out + (size_t)t * 5;
    bo[0] = y1; bo[1] = x1; bo[2] = y2; bo[3] = x2; bo[4] = msk;
    float* so = out + BATCH * KOUT * 5 + (size_t)t * 2;
    so[0] = s; so[1] = msk;
    float* lo = out + BATCH * KOUT * 7 + (size_t)t * 3;
    lo[0] = l0o; lo[1] = l1o; lo[2] = msk;
}

// ---------------------------------------------------------------------------
extern "C" void kernel_launch(void* const* d_in, const int* in_sizes, int n_in,
                              void* d_out, int out_size, void* d_ws, size_t ws_size,
                              hipStream_t stream) {
    const float* deltas  = (const float*)d_in[0];
    const float* logits  = (const float*)d_in[1];
    const float* anchors = (const float*)d_in[2];
    const int*   vai     = (const int*)d_in[3];
    float* out = (float*)d_out;

    // workspace layout (cap=1024 is ~23 sigma above the ~561 mean bucket fill)
    int cap = 1024;
    auto need = [&](int c) -> size_t {
        size_t o = (size_t)BATCH * NCOL * 4 * 3;  // cand_count, cntA, cntB
        o = (o + 15) & ~(size_t)15;
        o += (size_t)BATCH * NCOL * c * 16;       // cand (also merge pong)
        o += (size_t)BATCH * NCOL * KOUT * 8;     // surv (merge ping)
        return o;
    };
    while (cap > 256 && need(cap) > ws_size) cap >>= 1;

    char* ws = (char*)d_ws;
    size_t off = 0;
    int* cand_count = (int*)(ws + off); off += (size_t)BATCH * NCOL * 4;
    int* cntA       = (int*)(ws + off); off += (size_t)BATCH * NCOL * 4;  // surv_count
    int* cntB       = (int*)(ws + off); off += (size_t)BATCH * NCOL * 4;
    off = (off + 15) & ~(size_t)15;
    float4* cand = (float4*)(ws + off); off += (size_t)BATCH * NCOL * cap * 16;
    u64* surv = (u64*)(ws + off);
    u64* pong = (u64*)cand;  // cand dead after k_nms; >= 4.1 MB even at cap=256

    hipMemsetAsync(cand_count, 0, (size_t)BATCH * NCOL * 4, stream);
    k_filter<<<(BATCH * NN / GG) / 256, 256, 0, stream>>>(
        deltas, logits, anchors, vai, cand_count, cand, cap);
    k_nms<<<BATCH * NCOL, 64, 0, stream>>>(cand_count, cand, surv, cntA, cap);
    // 6-level pairwise merge tree: surv/cntA <-> pong/cntB; final in surv/cntA
    k_mergeL<<<BATCH * 32, 256, 0, stream>>>(surv, cntA, pong, cntB, 32);
    k_mergeL<<<BATCH * 16, 256, 0, stream>>>(pong, cntB, surv, cntA, 16);
    k_mergeL<<<BATCH *  8, 256, 0, stream>>>(surv, cntA, pong, cntB,  8);
    k_mergeL<<<BATCH *  4, 256, 0, stream>>>(pong, cntB, surv, cntA,  4);
    k_mergeL<<<BATCH *  2, 256, 0, stream>>>(surv, cntA, pong, cntB,  2);
    k_mergeL<<<BATCH *  1, 256, 0, stream>>>(pong, cntB, surv, cntA,  1);
    k_out<<<(BATCH * KOUT + 255) / 256, 256, 0, stream>>>(
        surv, cntA, deltas, logits, anchors, vai, out);
}